// Round 11
// baseline (359.686 us; speedup 1.0000x reference)
//
#include <hip/hip_runtime.h>

#define N_NODES 65536
#define B_G     16
#define NPG_    4096
#define H_H     2
#define D_D     64
#define HD      128
#define E_E     524288
#define D_OUT   64

// ---------------- degree / CSR build ----------------

__global__ void deg_kernel(const int* __restrict__ col, int* __restrict__ degi) {
    int e = blockIdx.x * 256 + threadIdx.x;
    if (e < E_E) atomicAdd(&degi[col[e]], 1);
}

__global__ void scan1(const int* __restrict__ degi, int* __restrict__ ptr,
                      int* __restrict__ bsums, float* __restrict__ dinv) {
    __shared__ int lds[256];
    int t = threadIdx.x;
    int i = blockIdx.x * 256 + t;
    int v = degi[i];
    dinv[i] = (v > 0) ? (1.0f / sqrtf((float)v)) : 0.0f;
    lds[t] = v;
    __syncthreads();
    for (int off = 1; off < 256; off <<= 1) {
        int tmp = (t >= off) ? lds[t - off] : 0;
        __syncthreads();
        lds[t] += tmp;
        __syncthreads();
    }
    ptr[i] = lds[t] - v;
    if (t == 255) bsums[blockIdx.x] = lds[255];
}

__global__ void scan3(int* __restrict__ ptr, const int* __restrict__ bsums) {
    __shared__ int red[256];
    int t = threadIdx.x;
    red[t] = (t < (int)blockIdx.x) ? bsums[t] : 0;
    __syncthreads();
    for (int off = 128; off > 0; off >>= 1) {
        if (t < off) red[t] += red[t + off];
        __syncthreads();
    }
    int i = blockIdx.x * 256 + t;
    ptr[i] += red[0];
    if (i == 0) ptr[N_NODES] = E_E;
}

__global__ void scatter_kernel(const int* __restrict__ row, const int* __restrict__ col,
                               const int* __restrict__ ptr, int* __restrict__ cursor,
                               const float* __restrict__ dinv,
                               int2* __restrict__ ep) {
    int e = blockIdx.x * 256 + threadIdx.x;
    if (e < E_E) {
        int c = col[e], r = row[e];
        int p = ptr[c] + atomicAdd(&cursor[c], 1);
        ep[p] = make_int2(r, __float_as_int(dinv[c] * dinv[r]));
    }
}

// ---------------- q/k projection + fused L2-normalize ----------------
// 8 nodes x 8 cols per thread (R = 256 FMA / 16 b128 -> FMA~balanced).
// Block = 128 nodes, q or k (bid&1). Node interleave ns+16i keeps x banks
// distinct across ns-groups; xt swizzled by node&7 (no pad, 32KB exact).
__global__ __launch_bounds__(256, 2) void proj_kernel(
    const float* __restrict__ x,
    const float* __restrict__ Wq, const float* __restrict__ bq,
    const float* __restrict__ Wk, const float* __restrict__ bk,
    float* __restrict__ qs, float* __restrict__ ks) {
    __shared__ float4 wt4[16 * 128];   // 32 KB [k4][col]
    __shared__ float4 xt4[128 * 16];   // 32 KB [node][k4^(node&7)]
    int t = threadIdx.x;
    int qk = blockIdx.x & 1;
    int nb = (blockIdx.x >> 1) * 128;
    const float* W = qk ? Wk : Wq;
    const float* bias = qk ? bk : bq;
    float* outp = qk ? ks : qs;

    for (int i = t; i < 2048; i += 256) {
        int k4 = i >> 7, c = i & 127;
        wt4[i] = make_float4(W[(4 * k4 + 0) * 128 + c], W[(4 * k4 + 1) * 128 + c],
                             W[(4 * k4 + 2) * 128 + c], W[(4 * k4 + 3) * 128 + c]);
    }
    const float4* xg = (const float4*)(x + (size_t)nb * 64);
    for (int i = t; i < 2048; i += 256) {
        int node = i >> 4, k4 = i & 15;
        xt4[node * 16 + (k4 ^ (node & 7))] = xg[i];
    }
    __syncthreads();

    int cg = t & 15;
    int ns = t >> 4;                 // 0..15; nodes ns + 16*i
    int sw = ns & 7;                 // node&7 for all of this thread's nodes

    float acc[8][8];
#pragma unroll
    for (int i = 0; i < 8; ++i)
#pragma unroll
        for (int j = 0; j < 8; ++j) acc[i][j] = 0.f;

    for (int k4 = 0; k4 < 16; ++k4) {
        float4 wv[8];
#pragma unroll
        for (int j = 0; j < 8; ++j) wv[j] = wt4[k4 * 128 + cg + 16 * j];
        int kx = k4 ^ sw;
#pragma unroll
        for (int i = 0; i < 8; ++i) {
            float4 xv = xt4[(ns + 16 * i) * 16 + kx];
#pragma unroll
            for (int j = 0; j < 8; ++j)
                acc[i][j] += wv[j].x * xv.x + wv[j].y * xv.y +
                             wv[j].z * xv.z + wv[j].w * xv.w;
        }
    }

    float bcol[8];
#pragma unroll
    for (int j = 0; j < 8; ++j) bcol[j] = bias[cg + 16 * j];

#pragma unroll
    for (int i = 0; i < 8; ++i) {
#pragma unroll
        for (int j = 0; j < 8; ++j) acc[i][j] += bcol[j];
        float s0 = acc[i][0] * acc[i][0] + acc[i][1] * acc[i][1] +
                   acc[i][2] * acc[i][2] + acc[i][3] * acc[i][3];
        float s1 = acc[i][4] * acc[i][4] + acc[i][5] * acc[i][5] +
                   acc[i][6] * acc[i][6] + acc[i][7] * acc[i][7];
#pragma unroll
        for (int off = 8; off > 0; off >>= 1) {
            s0 += __shfl_xor(s0, off);
            s1 += __shfl_xor(s1, off);
        }
        float r0 = rsqrtf(s0), r1 = rsqrtf(s1);
        size_t base = (size_t)(nb + ns + 16 * i) * 128 + cg;
#pragma unroll
        for (int j = 0; j < 4; ++j) outp[base + 16 * j] = acc[i][j] * r0;
#pragma unroll
        for (int j = 4; j < 8; ++j) outp[base + 16 * j] = acc[i][j] * r1;
    }
}

// ---------------- kvs stage A: per-block partials (no atomics) ----------------
__global__ __launch_bounds__(256) void kvs_part(
    const float* __restrict__ ks, const float* __restrict__ x,
    float* __restrict__ partials, float* __restrict__ ksum, float* __restrict__ xsum) {
    int bid = blockIdx.x;
    int chunk = bid & 31;
    int bh = bid >> 5;
    int b = bh >> 1, h = bh & 1;
    int t = threadIdx.x;
    int mrow = t >> 4, dcol = t & 15;
    int m0 = mrow * 4, d0 = dcol * 4;
    __shared__ float kl[32 * 64];
    __shared__ float xl[32 * 64];
    float acc[4][4] = {{0}};
    float ksacc[4] = {0, 0, 0, 0};
    float xsacc[4] = {0, 0, 0, 0};
    int node0 = b * NPG_ + chunk * 128;
    for (int s = 0; s < 4; ++s) {
        int nb = node0 + s * 32;
        for (int i = t; i < 512; i += 256) {
            int l = i >> 4, q = i & 15;
            ((float4*)kl)[i] = *(const float4*)(ks + (size_t)(nb + l) * 128 + h * 64 + q * 4);
        }
        const float4* xg = (const float4*)(x + (size_t)nb * 64);
        for (int i = t; i < 512; i += 256) ((float4*)xl)[i] = xg[i];
        __syncthreads();
        for (int l = 0; l < 32; ++l) {
            float4 kv = *(float4*)(kl + l * 64 + m0);
            float4 xv = *(float4*)(xl + l * 64 + d0);
            float kk[4] = {kv.x, kv.y, kv.z, kv.w};
            float xx[4] = {xv.x, xv.y, xv.z, xv.w};
#pragma unroll
            for (int i = 0; i < 4; ++i)
#pragma unroll
                for (int j = 0; j < 4; ++j) acc[i][j] += kk[i] * xx[j];
            if (dcol == 0) {
#pragma unroll
                for (int i = 0; i < 4; ++i) ksacc[i] += kk[i];
            }
            if (mrow == 0) {
#pragma unroll
                for (int j = 0; j < 4; ++j) xsacc[j] += xx[j];
            }
        }
        __syncthreads();
    }
    float* pout = partials + (size_t)bid * 4096;
#pragma unroll
    for (int i = 0; i < 4; ++i)
        *(float4*)(pout + (m0 + i) * 64 + d0) =
            make_float4(acc[i][0], acc[i][1], acc[i][2], acc[i][3]);
    if (dcol == 0) {
#pragma unroll
        for (int i = 0; i < 4; ++i) atomicAdd(&ksum[bh * 64 + m0 + i], ksacc[i]);
    }
    if (mrow == 0 && h == 0) {
#pragma unroll
        for (int j = 0; j < 4; ++j) atomicAdd(&xsum[b * 64 + d0 + j], xsacc[j]);
    }
}

__global__ __launch_bounds__(256) void kvs_reduce(
    const float* __restrict__ partials, float* __restrict__ kvs) {
    int i = blockIdx.x * 256 + threadIdx.x;
    int bh = i >> 12, elem = i & 4095;
    const float* p = partials + (size_t)bh * 32 * 4096 + elem;
    float s = 0.f;
#pragma unroll
    for (int c = 0; c < 32; ++c) s += p[c * 4096];
    kvs[i] = s;
}

// ---------------- attention: GEMM-style q_tile @ kvs, den fused ----------------
// Block = 128 nodes x 1 head. Thread = 8 nodes x 4 d-cols; full dots in-thread
// (no shuffles). kvs-frag wt4 16KB + swizzled q-tile 32KB.
__global__ __launch_bounds__(256, 3) void attn_kernel(
    const float* __restrict__ qs, const float* __restrict__ kvs,
    const float* __restrict__ ksum, const float* __restrict__ xsum,
    float* __restrict__ attn) {
    __shared__ float4 wt4[16 * 64];    // 16 KB [k4][d] packs kvs[4k4+c][d]
    __shared__ float4 xt4[128 * 16];   // 32 KB q [node][k4^(node&7)]
    __shared__ float4 ksv[16];
    __shared__ float xsv[64];
    int bid = blockIdx.x;
    int h = bid & 1;
    int nb = (bid >> 1) * 128;
    int b = nb >> 12;
    int bh = b * 2 + h;
    int t = threadIdx.x;

    const float* kvp = kvs + (size_t)bh * 4096;
    for (int i = t; i < 1024; i += 256) {
        int k4 = i >> 6, d = i & 63;
        wt4[i] = make_float4(kvp[(4 * k4 + 0) * 64 + d], kvp[(4 * k4 + 1) * 64 + d],
                             kvp[(4 * k4 + 2) * 64 + d], kvp[(4 * k4 + 3) * 64 + d]);
    }
    for (int i = t; i < 2048; i += 256) {
        int node = i >> 4, k4 = i & 15;
        xt4[node * 16 + (k4 ^ (node & 7))] =
            *(const float4*)(qs + (size_t)(nb + node) * 128 + h * 64 + 4 * k4);
    }
    if (t < 16) ksv[t] = *(const float4*)(ksum + bh * 64 + 4 * t);
    if (t < 64) xsv[t] = xsum[b * 64 + t];
    __syncthreads();

    int cg = t & 15;
    int ns = t >> 4;
    int sw = ns & 7;

    float acc[8][4];
    float den[8];
#pragma unroll
    for (int i = 0; i < 8; ++i) {
        den[i] = 0.f;
#pragma unroll
        for (int j = 0; j < 4; ++j) acc[i][j] = 0.f;
    }

    for (int k4 = 0; k4 < 16; ++k4) {
        float4 kv = ksv[k4];
        float4 wv[4];
#pragma unroll
        for (int j = 0; j < 4; ++j) wv[j] = wt4[k4 * 64 + cg + 16 * j];
        int kx = k4 ^ sw;
#pragma unroll
        for (int i = 0; i < 8; ++i) {
            float4 xv = xt4[(ns + 16 * i) * 16 + kx];
            den[i] += kv.x * xv.x + kv.y * xv.y + kv.z * xv.z + kv.w * xv.w;
#pragma unroll
            for (int j = 0; j < 4; ++j)
                acc[i][j] += wv[j].x * xv.x + wv[j].y * xv.y +
                             wv[j].z * xv.z + wv[j].w * xv.w;
        }
    }

    float xs_d[4];
#pragma unroll
    for (int j = 0; j < 4; ++j) xs_d[j] = xsv[cg + 16 * j];

#pragma unroll
    for (int i = 0; i < 8; ++i) {
        float inv = 1.0f / (den[i] + 16.0f);
        size_t base = (size_t)(nb + ns + 16 * i) * 128 + h * 64 + cg;
#pragma unroll
        for (int j = 0; j < 4; ++j)
            attn[base + 16 * j] = (acc[i][j] + xs_d[j]) * inv;
    }
}

// ---------------- a = attn @ Wo (R10, proven) ----------------
__global__ __launch_bounds__(256) void awo_kernel(
    const float* __restrict__ attn, const float* __restrict__ Wo,
    float* __restrict__ a) {
    __shared__ float4 wt4[32 * 64];
    __shared__ float4 xt4[64 * 32];
    int t = threadIdx.x;
    int nb = blockIdx.x * 64;

    for (int i = t; i < 2048; i += 256) {
        int k4 = i >> 6, c = i & 63;
        wt4[i] = make_float4(Wo[(4 * k4 + 0) * 64 + c], Wo[(4 * k4 + 1) * 64 + c],
                             Wo[(4 * k4 + 2) * 64 + c], Wo[(4 * k4 + 3) * 64 + c]);
    }
    const float4* ag = (const float4*)(attn + (size_t)nb * 128);
    for (int i = t; i < 2048; i += 256) xt4[i] = ag[i];
    __syncthreads();

    int cg = t & 15;
    int ns = t >> 4;
    int s = ns & 3;
    int n_t = ns * 4;

    float acc[4][4] = {{0.f}};
#pragma unroll 4
    for (int k4 = 0; k4 < 32; ++k4) {
        int kk = k4 ^ s;
        float4 xv0 = xt4[(n_t + 0) * 32 + kk];
        float4 xv1 = xt4[(n_t + 1) * 32 + kk];
        float4 xv2 = xt4[(n_t + 2) * 32 + kk];
        float4 xv3 = xt4[(n_t + 3) * 32 + kk];
#pragma unroll
        for (int j = 0; j < 4; ++j) {
            float4 wv = wt4[kk * 64 + cg + 16 * j];
            acc[0][j] += wv.x * xv0.x + wv.y * xv0.y + wv.z * xv0.z + wv.w * xv0.w;
            acc[1][j] += wv.x * xv1.x + wv.y * xv1.y + wv.z * xv1.z + wv.w * xv1.w;
            acc[2][j] += wv.x * xv2.x + wv.y * xv2.y + wv.z * xv2.z + wv.w * xv2.w;
            acc[3][j] += wv.x * xv3.x + wv.y * xv3.y + wv.z * xv3.z + wv.w * xv3.w;
        }
    }
#pragma unroll
    for (int i = 0; i < 4; ++i)
#pragma unroll
        for (int j = 0; j < 4; ++j)
            a[(size_t)(nb + n_t + i) * 64 + cg + 16 * j] = acc[i][j];
}

// ---------------- y0 = x @ (Wo_top + Wo_bot) (R10, proven) ----------------
__global__ __launch_bounds__(256) void y0_kernel(
    const float* __restrict__ x, const float* __restrict__ Wo,
    float* __restrict__ y0) {
    __shared__ float4 wt4[16 * 64];
    __shared__ float4 xt4[64 * 16];
    int t = threadIdx.x;
    int nb = blockIdx.x * 64;

    for (int i = t; i < 1024; i += 256) {
        int k4 = i >> 6, c = i & 63;
        wt4[i] = make_float4(
            Wo[(4 * k4 + 0) * 64 + c] + Wo[(4 * k4 + 64) * 64 + c],
            Wo[(4 * k4 + 1) * 64 + c] + Wo[(4 * k4 + 65) * 64 + c],
            Wo[(4 * k4 + 2) * 64 + c] + Wo[(4 * k4 + 66) * 64 + c],
            Wo[(4 * k4 + 3) * 64 + c] + Wo[(4 * k4 + 67) * 64 + c]);
    }
    const float4* xg = (const float4*)(x + (size_t)nb * 64);
    for (int i = t; i < 1024; i += 256) xt4[i] = xg[i];
    __syncthreads();

    int cg = t & 15;
    int ns = t >> 4;
    int s = ns & 3;
    int n_t = ns * 4;

    float acc[4][4] = {{0.f}};
#pragma unroll 4
    for (int k4 = 0; k4 < 16; ++k4) {
        int kk = k4 ^ s;
        float4 xv0 = xt4[(n_t + 0) * 16 + kk];
        float4 xv1 = xt4[(n_t + 1) * 16 + kk];
        float4 xv2 = xt4[(n_t + 2) * 16 + kk];
        float4 xv3 = xt4[(n_t + 3) * 16 + kk];
#pragma unroll
        for (int j = 0; j < 4; ++j) {
            float4 wv = wt4[kk * 64 + cg + 16 * j];
            acc[0][j] += wv.x * xv0.x + wv.y * xv0.y + wv.z * xv0.z + wv.w * xv0.w;
            acc[1][j] += wv.x * xv1.x + wv.y * xv1.y + wv.z * xv1.z + wv.w * xv1.w;
            acc[2][j] += wv.x * xv2.x + wv.y * xv2.y + wv.z * xv2.z + wv.w * xv2.w;
            acc[3][j] += wv.x * xv3.x + wv.y * xv3.y + wv.z * xv3.z + wv.w * xv3.w;
        }
    }
#pragma unroll
    for (int i = 0; i < 4; ++i)
#pragma unroll
        for (int j = 0; j < 4; ++j)
            y0[(size_t)(nb + n_t + i) * 64 + cg + 16 * j] = acc[i][j];
}

// ---------------- GCN step in 64-col space: single 16-slot batch ----------------
template <int LAST>
__global__ __launch_bounds__(256) void gcn64_kernel(
    const float* __restrict__ yin, const float* __restrict__ a,
    const int* __restrict__ ptr, const int2* __restrict__ ep,
    float* __restrict__ yout, const float* __restrict__ bo) {
    int bid = blockIdx.x;
    int lbid = (bid & 7) * (N_NODES / 16 / 8) + (bid >> 3);
    int t = threadIdx.x;
    int n = lbid * 16 + (t >> 4);
    int lg = t & 15;
    int c4 = lg * 4;
    int e0 = ptr[n], e1 = ptr[n + 1];
    int cnt = e1 - e0;
    float4 acc = make_float4(0.f, 0.f, 0.f, 0.f);

    int2 q[16];
#pragma unroll
    for (int i = 0; i < 16; ++i) {
        int ee = e0 + i;
        if (ee > e1 - 1) ee = e1 - 1;
        if (ee < 0) ee = 0;
        q[i] = ep[ee];
    }
#pragma unroll
    for (int i = 0; i < 16; ++i) {
        if (i < cnt) {
            float v = __int_as_float(q[i].y);
            float4 xv = *(const float4*)(yin + (size_t)q[i].x * 64 + c4);
            acc.x += v * xv.x; acc.y += v * xv.y;
            acc.z += v * xv.z; acc.w += v * xv.w;
        }
    }
    for (int e = e0 + 16; e < e1; ++e) {
        int2 qq = ep[e];
        float v = __int_as_float(qq.y);
        float4 xv = *(const float4*)(yin + (size_t)qq.x * 64 + c4);
        acc.x += v * xv.x; acc.y += v * xv.y;
        acc.z += v * xv.z; acc.w += v * xv.w;
    }

    size_t idx = (size_t)n * 64 + c4;
    float4 self = *(const float4*)(yin + idx);
    float4 at = *(const float4*)(a + idx);
    float4 o;
    o.x = self.x + 0.5f * acc.x + 0.5f * at.x;
    o.y = self.y + 0.5f * acc.y + 0.5f * at.y;
    o.z = self.z + 0.5f * acc.z + 0.5f * at.z;
    o.w = self.w + 0.5f * acc.w + 0.5f * at.w;
    if (LAST) {
        float4 bv = *(const float4*)(bo + c4);
        o.x = (o.x + bv.x) * 0.5f;
        o.y = (o.y + bv.y) * 0.5f;
        o.z = (o.z + bv.z) * 0.5f;
        o.w = (o.w + bv.w) * 0.5f;
    }
    *(float4*)(yout + idx) = o;
}

// ---------------- launch ----------------

extern "C" void kernel_launch(void* const* d_in, const int* in_sizes, int n_in,
                              void* d_out, int out_size, void* d_ws, size_t ws_size,
                              hipStream_t stream) {
    const float* x  = (const float*)d_in[0];
    const int* ei   = (const int*)d_in[1];
    const float* Wq = (const float*)d_in[3];
    const float* bq = (const float*)d_in[4];
    const float* Wk = (const float*)d_in[5];
    const float* bk = (const float*)d_in[6];
    const float* Wo = (const float*)d_in[7];
    const float* bo = (const float*)d_in[8];
    float* out = (float*)d_out;

    const int* row = ei;
    const int* col = ei + E_E;

    float* bufA = (float*)d_ws;
    float* bufB = bufA + (size_t)N_NODES * HD;
    float* bufC = bufB + (size_t)N_NODES * HD;
    int2*  ep   = (int2*)(bufC + (size_t)N_NODES * HD);
    float* kvs  = (float*)(ep + E_E);
    float* ksum = kvs + 131072;
    float* xsum = ksum + 2048;
    float* dinv = xsum + 1024;
    int* degi   = (int*)(dinv + N_NODES);
    int* cursor = degi + N_NODES;
    int* ptr    = cursor + N_NODES;
    int* bsums  = ptr + N_NODES + 1;

    float* a_  = bufA;
    float* yA  = bufA + (size_t)N_NODES * 64;
    float* yB  = bufB;

    hipMemsetAsync(degi, 0, (size_t)N_NODES * 2 * 4, stream);
    hipMemsetAsync(ksum, 0, (size_t)(2048 + 1024) * 4, stream);

    deg_kernel<<<E_E / 256, 256, 0, stream>>>(col, degi);
    scan1<<<N_NODES / 256, 256, 0, stream>>>(degi, ptr, bsums, dinv);
    scan3<<<N_NODES / 256, 256, 0, stream>>>(ptr, bsums);
    scatter_kernel<<<E_E / 256, 256, 0, stream>>>(row, col, ptr, cursor, dinv, ep);

    proj_kernel<<<1024, 256, 0, stream>>>(x, Wq, bq, Wk, bk, bufA, bufB);

    kvs_part<<<1024, 256, 0, stream>>>(bufB, x, bufC, ksum, xsum);
    kvs_reduce<<<512, 256, 0, stream>>>(bufC, kvs);
    attn_kernel<<<1024, 256, 0, stream>>>(bufA, kvs, ksum, xsum, bufC);

    awo_kernel<<<1024, 256, 0, stream>>>(bufC, Wo, a_);
    y0_kernel<<<1024, 256, 0, stream>>>(x, Wo, yA);

    gcn64_kernel<0><<<N_NODES / 16, 256, 0, stream>>>(yA, a_, ptr, ep, yB, bo);
    gcn64_kernel<0><<<N_NODES / 16, 256, 0, stream>>>(yB, a_, ptr, ep, yA, bo);
    gcn64_kernel<0><<<N_NODES / 16, 256, 0, stream>>>(yA, a_, ptr, ep, yB, bo);
    gcn64_kernel<1><<<N_NODES / 16, 256, 0, stream>>>(yB, a_, ptr, ep, out, bo);
}

// Round 13
// 336.276 us; speedup vs baseline: 1.0696x; 1.0696x over previous
//
#include <hip/hip_runtime.h>

#define N_NODES 65536
#define B_G     16
#define NPG_    4096
#define H_H     2
#define D_D     64
#define HD      128
#define E_E     524288
#define D_OUT   64

// ---------------- degree / CSR build ----------------

__global__ void deg_kernel(const int* __restrict__ col, int* __restrict__ degi) {
    int e = blockIdx.x * 256 + threadIdx.x;
    if (e < E_E) atomicAdd(&degi[col[e]], 1);
}

__global__ void scan1(const int* __restrict__ degi, int* __restrict__ ptr,
                      int* __restrict__ bsums, float* __restrict__ dinv) {
    __shared__ int lds[256];
    int t = threadIdx.x;
    int i = blockIdx.x * 256 + t;
    int v = degi[i];
    dinv[i] = (v > 0) ? (1.0f / sqrtf((float)v)) : 0.0f;
    lds[t] = v;
    __syncthreads();
    for (int off = 1; off < 256; off <<= 1) {
        int tmp = (t >= off) ? lds[t - off] : 0;
        __syncthreads();
        lds[t] += tmp;
        __syncthreads();
    }
    ptr[i] = lds[t] - v;
    if (t == 255) bsums[blockIdx.x] = lds[255];
}

__global__ void scan3(int* __restrict__ ptr, const int* __restrict__ bsums) {
    __shared__ int red[256];
    int t = threadIdx.x;
    red[t] = (t < (int)blockIdx.x) ? bsums[t] : 0;
    __syncthreads();
    for (int off = 128; off > 0; off >>= 1) {
        if (t < off) red[t] += red[t + off];
        __syncthreads();
    }
    int i = blockIdx.x * 256 + t;
    ptr[i] += red[0];
    if (i == 0) ptr[N_NODES] = E_E;
}

__global__ void scatter_kernel(const int* __restrict__ row, const int* __restrict__ col,
                               const int* __restrict__ ptr, int* __restrict__ cursor,
                               const float* __restrict__ dinv,
                               int2* __restrict__ ep) {
    int e = blockIdx.x * 256 + threadIdx.x;
    if (e < E_E) {
        int c = col[e], r = row[e];
        int p = ptr[c] + atomicAdd(&cursor[c], 1);
        ep[p] = make_int2(r, __float_as_int(dinv[c] * dinv[r]));
    }
}

// ---------------- q/k projection + fused L2-normalize ----------------
// Head-split: block = 128 nodes x 64 cols (bid&1 = q/k, bid>>1&1 = head).
// LDS 48KB -> 3 blocks/CU. Thread = 8 nodes x 4 cols. Write-swizzle node&7 is
// consistent: this thread's nodes are ns+16i so node&7 == ns&7 (constant).
__global__ __launch_bounds__(256) void proj_kernel(
    const float* __restrict__ x,
    const float* __restrict__ Wq, const float* __restrict__ bq,
    const float* __restrict__ Wk, const float* __restrict__ bk,
    float* __restrict__ qs, float* __restrict__ ks) {
    __shared__ float4 wt4[16 * 64];    // 16 KB [k4][c] = W[4k4+r][h*64+c]
    __shared__ float4 xt4[128 * 16];   // 32 KB [node][k4^(node&7)]
    int t = threadIdx.x;
    int qk = blockIdx.x & 1;
    int hh = (blockIdx.x >> 1) & 1;
    int nb = (blockIdx.x >> 2) * 128;
    const float* W = qk ? Wk : Wq;
    const float* bias = qk ? bk : bq;
    float* outp = qk ? ks : qs;

    for (int i = t; i < 1024; i += 256) {
        int k4 = i >> 6, c = i & 63;
        int cc = hh * 64 + c;
        wt4[i] = make_float4(W[(4 * k4 + 0) * 128 + cc], W[(4 * k4 + 1) * 128 + cc],
                             W[(4 * k4 + 2) * 128 + cc], W[(4 * k4 + 3) * 128 + cc]);
    }
    const float4* xg = (const float4*)(x + (size_t)nb * 64);
    for (int i = t; i < 2048; i += 256) {
        int node = i >> 4, k4 = i & 15;
        xt4[node * 16 + (k4 ^ (node & 7))] = xg[i];
    }
    __syncthreads();

    int cg = t & 15;
    int ns = t >> 4;
    int sw = ns & 7;

    float acc[8][4];
#pragma unroll
    for (int i = 0; i < 8; ++i)
#pragma unroll
        for (int j = 0; j < 4; ++j) acc[i][j] = 0.f;

    for (int k4 = 0; k4 < 16; ++k4) {
        float4 wv[4];
#pragma unroll
        for (int j = 0; j < 4; ++j) wv[j] = wt4[k4 * 64 + cg + 16 * j];
        int kx = k4 ^ sw;
#pragma unroll
        for (int i = 0; i < 8; ++i) {
            float4 xv = xt4[(ns + 16 * i) * 16 + kx];
#pragma unroll
            for (int j = 0; j < 4; ++j)
                acc[i][j] += wv[j].x * xv.x + wv[j].y * xv.y +
                             wv[j].z * xv.z + wv[j].w * xv.w;
        }
    }

    float bcol[4];
#pragma unroll
    for (int j = 0; j < 4; ++j) bcol[j] = bias[hh * 64 + cg + 16 * j];

#pragma unroll
    for (int i = 0; i < 8; ++i) {
#pragma unroll
        for (int j = 0; j < 4; ++j) acc[i][j] += bcol[j];
        float s = acc[i][0] * acc[i][0] + acc[i][1] * acc[i][1] +
                  acc[i][2] * acc[i][2] + acc[i][3] * acc[i][3];
#pragma unroll
        for (int off = 8; off > 0; off >>= 1) s += __shfl_xor(s, off);
        float r = rsqrtf(s);
        size_t base = (size_t)(nb + ns + 16 * i) * 128 + hh * 64 + cg;
#pragma unroll
        for (int j = 0; j < 4; ++j) outp[base + 16 * j] = acc[i][j] * r;
    }
}

// ---------------- kvs stage A: per-block partials (no atomics) ----------------
__global__ __launch_bounds__(256) void kvs_part(
    const float* __restrict__ ks, const float* __restrict__ x,
    float* __restrict__ partials, float* __restrict__ ksum, float* __restrict__ xsum) {
    int bid = blockIdx.x;
    int chunk = bid & 31;
    int bh = bid >> 5;
    int b = bh >> 1, h = bh & 1;
    int t = threadIdx.x;
    int mrow = t >> 4, dcol = t & 15;
    int m0 = mrow * 4, d0 = dcol * 4;
    __shared__ float kl[32 * 64];
    __shared__ float xl[32 * 64];
    float acc[4][4] = {{0}};
    float ksacc[4] = {0, 0, 0, 0};
    float xsacc[4] = {0, 0, 0, 0};
    int node0 = b * NPG_ + chunk * 128;
    for (int s = 0; s < 4; ++s) {
        int nb = node0 + s * 32;
        for (int i = t; i < 512; i += 256) {
            int l = i >> 4, q = i & 15;
            ((float4*)kl)[i] = *(const float4*)(ks + (size_t)(nb + l) * 128 + h * 64 + q * 4);
        }
        const float4* xg = (const float4*)(x + (size_t)nb * 64);
        for (int i = t; i < 512; i += 256) ((float4*)xl)[i] = xg[i];
        __syncthreads();
        for (int l = 0; l < 32; ++l) {
            float4 kv = *(float4*)(kl + l * 64 + m0);
            float4 xv = *(float4*)(xl + l * 64 + d0);
            float kk[4] = {kv.x, kv.y, kv.z, kv.w};
            float xx[4] = {xv.x, xv.y, xv.z, xv.w};
#pragma unroll
            for (int i = 0; i < 4; ++i)
#pragma unroll
                for (int j = 0; j < 4; ++j) acc[i][j] += kk[i] * xx[j];
            if (dcol == 0) {
#pragma unroll
                for (int i = 0; i < 4; ++i) ksacc[i] += kk[i];
            }
            if (mrow == 0) {
#pragma unroll
                for (int j = 0; j < 4; ++j) xsacc[j] += xx[j];
            }
        }
        __syncthreads();
    }
    float* pout = partials + (size_t)bid * 4096;
#pragma unroll
    for (int i = 0; i < 4; ++i)
        *(float4*)(pout + (m0 + i) * 64 + d0) =
            make_float4(acc[i][0], acc[i][1], acc[i][2], acc[i][3]);
    if (dcol == 0) {
#pragma unroll
        for (int i = 0; i < 4; ++i) atomicAdd(&ksum[bh * 64 + m0 + i], ksacc[i]);
    }
    if (mrow == 0 && h == 0) {
#pragma unroll
        for (int j = 0; j < 4; ++j) atomicAdd(&xsum[b * 64 + d0 + j], xsacc[j]);
    }
}

__global__ __launch_bounds__(256) void kvs_reduce(
    const float* __restrict__ partials, float* __restrict__ kvs) {
    int i = blockIdx.x * 256 + threadIdx.x;
    int bh = i >> 12, elem = i & 4095;
    const float* p = partials + (size_t)bh * 32 * 4096 + elem;
    float s = 0.f;
#pragma unroll
    for (int c = 0; c < 32; ++c) s += p[c * 4096];
    kvs[i] = s;
}

// ---------------- M_bh = KVS_bh @ Wo_h ; C_bh = xsum_b @ Wo_h ----------------
__global__ __launch_bounds__(256) void mwo_kernel(
    const float* __restrict__ kvs, const float* __restrict__ Wo,
    const float* __restrict__ xsum, float* __restrict__ M, float* __restrict__ C) {
    __shared__ float kv_l[64 * 64];
    __shared__ float wo_l[64 * 64];
    __shared__ float xs_l[64];
    int bh = blockIdx.x;
    int b = bh >> 1, h = bh & 1;
    int t = threadIdx.x;
    const float4* kvg = (const float4*)(kvs + (size_t)bh * 4096);
    for (int i = t; i < 1024; i += 256) ((float4*)kv_l)[i] = kvg[i];
    for (int i = t; i < 1024; i += 256) {
        int d = i >> 4;
        ((float4*)wo_l)[i] = *(const float4*)(Wo + (size_t)(h * 64 + d) * 64 + (i & 15) * 4);
    }
    if (t < 64) xs_l[t] = xsum[b * 64 + t];
    __syncthreads();

    int ccol = t & 15, mrow = t >> 4;
    int m0 = mrow * 4, c0 = ccol * 4;
    float acc[4][4] = {{0.f}};
    float cacc[4] = {0.f, 0.f, 0.f, 0.f};
    for (int d = 0; d < 64; ++d) {
        float4 wv = *(const float4*)(wo_l + d * 64 + c0);
        float kvv[4];
#pragma unroll
        for (int i = 0; i < 4; ++i) kvv[i] = kv_l[(m0 + i) * 64 + d];
#pragma unroll
        for (int i = 0; i < 4; ++i) {
            acc[i][0] += kvv[i] * wv.x; acc[i][1] += kvv[i] * wv.y;
            acc[i][2] += kvv[i] * wv.z; acc[i][3] += kvv[i] * wv.w;
        }
        if (mrow == 0) {
            float xv = xs_l[d];
            cacc[0] += xv * wv.x; cacc[1] += xv * wv.y;
            cacc[2] += xv * wv.z; cacc[3] += xv * wv.w;
        }
    }
    float* mo = M + (size_t)bh * 4096;
#pragma unroll
    for (int i = 0; i < 4; ++i)
        *(float4*)(mo + (m0 + i) * 64 + c0) =
            make_float4(acc[i][0], acc[i][1], acc[i][2], acc[i][3]);
    if (mrow == 0)
        *(float4*)(C + bh * 64 + c0) = make_float4(cacc[0], cacc[1], cacc[2], cacc[3]);
}

// ---------------- fused attn@Wo: a[n] = sum_h (q_h M_bh + C_bh)/den_h ----------------
// Linear xt4 store; XOR skew applied to the ITERATION ORDER only (kk used
// consistently for ksv, wt4, xt4) — awo-proven, permutation-invariant sum.
__global__ __launch_bounds__(256) void fatt_kernel(
    const float* __restrict__ qs, const float* __restrict__ M,
    const float* __restrict__ C, const float* __restrict__ ksum,
    float* __restrict__ a) {
    __shared__ float4 wt4[16 * 64];    // 16 KB [k4][c] packs M[4k4+r][c]
    __shared__ float4 xt4[64 * 16];    // 16 KB q [node][k4] (linear)
    __shared__ float4 ksv[16];
    __shared__ float csv[64];
    int nb = blockIdx.x * 64;
    int b = nb >> 12;
    int t = threadIdx.x;
    int cg = t & 15;
    int ns = t >> 4;
    int sw = ns & 3;
    int n_t = ns * 4;

    float acc[4][4] = {{0.f}};

    for (int h = 0; h < 2; ++h) {
        int bh = b * 2 + h;
        const float* mp = M + (size_t)bh * 4096;
        for (int i = t; i < 1024; i += 256) {
            int k4 = i >> 6, c = i & 63;
            wt4[i] = make_float4(mp[(4 * k4 + 0) * 64 + c], mp[(4 * k4 + 1) * 64 + c],
                                 mp[(4 * k4 + 2) * 64 + c], mp[(4 * k4 + 3) * 64 + c]);
        }
        for (int i = t; i < 1024; i += 256) {
            int node = i >> 4, k4 = i & 15;
            xt4[i] = *(const float4*)(qs + (size_t)(nb + node) * 128 + h * 64 + 4 * k4);
        }
        if (t < 16) ksv[t] = *(const float4*)(ksum + bh * 64 + 4 * t);
        if (t < 64) csv[t] = C[bh * 64 + t];
        __syncthreads();

        float pacc[4][4] = {{0.f}};
        float den[4] = {0.f, 0.f, 0.f, 0.f};
        for (int k4 = 0; k4 < 16; ++k4) {
            int kk = k4 ^ sw;
            float4 kv = ksv[kk];
            float4 wv[4];
#pragma unroll
            for (int j = 0; j < 4; ++j) wv[j] = wt4[kk * 64 + cg + 16 * j];
#pragma unroll
            for (int i = 0; i < 4; ++i) {
                float4 xv = xt4[(n_t + i) * 16 + kk];
                den[i] += kv.x * xv.x + kv.y * xv.y + kv.z * xv.z + kv.w * xv.w;
#pragma unroll
                for (int j = 0; j < 4; ++j)
                    pacc[i][j] += wv[j].x * xv.x + wv[j].y * xv.y +
                                  wv[j].z * xv.z + wv[j].w * xv.w;
            }
        }
        float cc[4];
#pragma unroll
        for (int j = 0; j < 4; ++j) cc[j] = csv[cg + 16 * j];
#pragma unroll
        for (int i = 0; i < 4; ++i) {
            float inv = 1.0f / (den[i] + 16.0f);
#pragma unroll
            for (int j = 0; j < 4; ++j) acc[i][j] += (pacc[i][j] + cc[j]) * inv;
        }
        __syncthreads();
    }

#pragma unroll
    for (int i = 0; i < 4; ++i)
#pragma unroll
        for (int j = 0; j < 4; ++j)
            a[(size_t)(nb + n_t + i) * 64 + cg + 16 * j] = acc[i][j];
}

// ---------------- y0 = x @ (Wo_top + Wo_bot) (R10, proven) ----------------
__global__ __launch_bounds__(256) void y0_kernel(
    const float* __restrict__ x, const float* __restrict__ Wo,
    float* __restrict__ y0) {
    __shared__ float4 wt4[16 * 64];
    __shared__ float4 xt4[64 * 16];
    int t = threadIdx.x;
    int nb = blockIdx.x * 64;

    for (int i = t; i < 1024; i += 256) {
        int k4 = i >> 6, c = i & 63;
        wt4[i] = make_float4(
            Wo[(4 * k4 + 0) * 64 + c] + Wo[(4 * k4 + 64) * 64 + c],
            Wo[(4 * k4 + 1) * 64 + c] + Wo[(4 * k4 + 65) * 64 + c],
            Wo[(4 * k4 + 2) * 64 + c] + Wo[(4 * k4 + 66) * 64 + c],
            Wo[(4 * k4 + 3) * 64 + c] + Wo[(4 * k4 + 67) * 64 + c]);
    }
    const float4* xg = (const float4*)(x + (size_t)nb * 64);
    for (int i = t; i < 1024; i += 256) xt4[i] = xg[i];
    __syncthreads();

    int cg = t & 15;
    int ns = t >> 4;
    int s = ns & 3;
    int n_t = ns * 4;

    float acc[4][4] = {{0.f}};
#pragma unroll 4
    for (int k4 = 0; k4 < 16; ++k4) {
        int kk = k4 ^ s;
        float4 xv0 = xt4[(n_t + 0) * 16 + kk];
        float4 xv1 = xt4[(n_t + 1) * 16 + kk];
        float4 xv2 = xt4[(n_t + 2) * 16 + kk];
        float4 xv3 = xt4[(n_t + 3) * 16 + kk];
#pragma unroll
        for (int j = 0; j < 4; ++j) {
            float4 wv = wt4[kk * 64 + cg + 16 * j];
            acc[0][j] += wv.x * xv0.x + wv.y * xv0.y + wv.z * xv0.z + wv.w * xv0.w;
            acc[1][j] += wv.x * xv1.x + wv.y * xv1.y + wv.z * xv1.z + wv.w * xv1.w;
            acc[2][j] += wv.x * xv2.x + wv.y * xv2.y + wv.z * xv2.z + wv.w * xv2.w;
            acc[3][j] += wv.x * xv3.x + wv.y * xv3.y + wv.z * xv3.z + wv.w * xv3.w;
        }
    }
#pragma unroll
    for (int i = 0; i < 4; ++i)
#pragma unroll
        for (int j = 0; j < 4; ++j)
            y0[(size_t)(nb + n_t + i) * 64 + cg + 16 * j] = acc[i][j];
}

// ---------------- GCN step in 64-col space: single 16-slot batch ----------------
template <int LAST>
__global__ __launch_bounds__(256) void gcn64_kernel(
    const float* __restrict__ yin, const float* __restrict__ a,
    const int* __restrict__ ptr, const int2* __restrict__ ep,
    float* __restrict__ yout, const float* __restrict__ bo) {
    int bid = blockIdx.x;
    int lbid = (bid & 7) * (N_NODES / 16 / 8) + (bid >> 3);
    int t = threadIdx.x;
    int n = lbid * 16 + (t >> 4);
    int lg = t & 15;
    int c4 = lg * 4;
    int e0 = ptr[n], e1 = ptr[n + 1];
    int cnt = e1 - e0;
    float4 acc = make_float4(0.f, 0.f, 0.f, 0.f);

    int2 q[16];
#pragma unroll
    for (int i = 0; i < 16; ++i) {
        int ee = e0 + i;
        if (ee > e1 - 1) ee = e1 - 1;
        if (ee < 0) ee = 0;
        q[i] = ep[ee];
    }
#pragma unroll
    for (int i = 0; i < 16; ++i) {
        if (i < cnt) {
            float v = __int_as_float(q[i].y);
            float4 xv = *(const float4*)(yin + (size_t)q[i].x * 64 + c4);
            acc.x += v * xv.x; acc.y += v * xv.y;
            acc.z += v * xv.z; acc.w += v * xv.w;
        }
    }
    for (int e = e0 + 16; e < e1; ++e) {
        int2 qq = ep[e];
        float v = __int_as_float(qq.y);
        float4 xv = *(const float4*)(yin + (size_t)qq.x * 64 + c4);
        acc.x += v * xv.x; acc.y += v * xv.y;
        acc.z += v * xv.z; acc.w += v * xv.w;
    }

    size_t idx = (size_t)n * 64 + c4;
    float4 self = *(const float4*)(yin + idx);
    float4 at = *(const float4*)(a + idx);
    float4 o;
    o.x = self.x + 0.5f * acc.x + 0.5f * at.x;
    o.y = self.y + 0.5f * acc.y + 0.5f * at.y;
    o.z = self.z + 0.5f * acc.z + 0.5f * at.z;
    o.w = self.w + 0.5f * acc.w + 0.5f * at.w;
    if (LAST) {
        float4 bv = *(const float4*)(bo + c4);
        o.x = (o.x + bv.x) * 0.5f;
        o.y = (o.y + bv.y) * 0.5f;
        o.z = (o.z + bv.z) * 0.5f;
        o.w = (o.w + bv.w) * 0.5f;
    }
    *(float4*)(yout + idx) = o;
}

// ---------------- launch ----------------

extern "C" void kernel_launch(void* const* d_in, const int* in_sizes, int n_in,
                              void* d_out, int out_size, void* d_ws, size_t ws_size,
                              hipStream_t stream) {
    const float* x  = (const float*)d_in[0];
    const int* ei   = (const int*)d_in[1];
    const float* Wq = (const float*)d_in[3];
    const float* bq = (const float*)d_in[4];
    const float* Wk = (const float*)d_in[5];
    const float* bk = (const float*)d_in[6];
    const float* Wo = (const float*)d_in[7];
    const float* bo = (const float*)d_in[8];
    float* out = (float*)d_out;

    const int* row = ei;
    const int* col = ei + E_E;

    // bufA: [a_ (N*64)] [yA / kvs-partials (N*64)]   — partials consumed by
    //        kvs_reduce BEFORE y0 writes yA, so they share the region.
    // bufB: ks -> yB ping-pong. bufC: qs.
    float* bufA = (float*)d_ws;
    float* bufB = bufA + (size_t)N_NODES * HD;
    float* bufC = bufB + (size_t)N_NODES * HD;
    int2*  ep   = (int2*)(bufC + (size_t)N_NODES * HD);
    float* kvs  = (float*)(ep + E_E);                  // 131072
    float* M    = kvs + 131072;                        // 131072
    float* Cc   = M + 131072;                          // 2048
    float* ksum = Cc + 2048;                           // 2048
    float* xsum = ksum + 2048;                         // 1024
    float* dinv = xsum + 1024;                         // N
    int* degi   = (int*)(dinv + N_NODES);              // N
    int* cursor = degi + N_NODES;                      // N
    int* ptr    = cursor + N_NODES;                    // N+1
    int* bsums  = ptr + N_NODES + 1;                   // 256

    float* qs_      = bufC;
    float* ks_      = bufB;
    float* a_       = bufA;
    float* yA       = bufA + (size_t)N_NODES * 64;
    float* partials = yA;                              // reused before y0
    float* yB       = bufB;

    hipMemsetAsync(degi, 0, (size_t)N_NODES * 2 * 4, stream);
    hipMemsetAsync(ksum, 0, (size_t)(2048 + 1024) * 4, stream);

    deg_kernel<<<E_E / 256, 256, 0, stream>>>(col, degi);
    scan1<<<N_NODES / 256, 256, 0, stream>>>(degi, ptr, bsums, dinv);
    scan3<<<N_NODES / 256, 256, 0, stream>>>(ptr, bsums);
    scatter_kernel<<<E_E / 256, 256, 0, stream>>>(row, col, ptr, cursor, dinv, ep);

    proj_kernel<<<2048, 256, 0, stream>>>(x, Wq, bq, Wk, bk, qs_, ks_);

    kvs_part<<<1024, 256, 0, stream>>>(ks_, x, partials, ksum, xsum);
    kvs_reduce<<<512, 256, 0, stream>>>(partials, kvs);
    mwo_kernel<<<32, 256, 0, stream>>>(kvs, Wo, xsum, M, Cc);
    fatt_kernel<<<1024, 256, 0, stream>>>(qs_, M, Cc, ksum, a_);

    y0_kernel<<<1024, 256, 0, stream>>>(x, Wo, yA);

    gcn64_kernel<0><<<N_NODES / 16, 256, 0, stream>>>(yA, a_, ptr, ep, yB, bo);
    gcn64_kernel<0><<<N_NODES / 16, 256, 0, stream>>>(yB, a_, ptr, ep, yA, bo);
    gcn64_kernel<0><<<N_NODES / 16, 256, 0, stream>>>(yA, a_, ptr, ep, yB, bo);
    gcn64_kernel<1><<<N_NODES / 16, 256, 0, stream>>>(yB, a_, ptr, ep, out, bo);
}